// Round 16
// baseline (59.781 us; speedup 1.0000x reference)
//
#include <hip/hip_runtime.h>
#include <hip/hip_bf16.h>
#include <math.h>

typedef float f32x4 __attribute__((ext_vector_type(4)));
typedef long  i64;

#define B_HALF 2048
#define N_TOT  4096
#define D_DIM  128
#define NGRP   32
#define NBLK   528   // triangular 32x32 tile grid (528 % 8 == 0)
#define KSTEPS 8     // K chunks of 64 (fp8: 64 B per row-chunk)
#define ROWB   512   // Gf8 row pitch in bytes (512 fp8 features)

// winner counter for the final reduction (zero at load; winner resets ->
// deterministic across graph replays; increment-only, nobody spins).
__device__ unsigned red_done;

// pack two floats -> two OCP e4m3 fp8 (low byte = first arg, RNE)
__device__ __forceinline__ short pk8(float x, float y) {
  return (short)__builtin_amdgcn_cvt_pk_fp8_f32(x, y, 0, false);
}

// ---------------------------------------------------------------------------
// P0: fp8-e4m3 features G + f32 a[]  (identical to R14).
// ---------------------------------------------------------------------------
__global__ __launch_bounds__(256) void prep_feat(
    const float* __restrict__ mu_x, const float* __restrict__ sigma_x,
    const float* __restrict__ mu_p, const float* __restrict__ sigma_p,
    unsigned char* __restrict__ Gf8, float* __restrict__ a) {
  const int tid = threadIdx.x;
  const int wv = tid >> 6;
  const int ln = tid & 63;
  const int d0 = ln * 2;
  const float SQ2 = 1.41421356237309515f;
#pragma unroll
  for (int rr = 0; rr < 16; rr += 4) {
    const int row = blockIdx.x * 16 + rr + wv;
    const float* mup = (row < B_HALF) ? mu_x : mu_p;
    const float* sgp = (row < B_HALF) ? sigma_x : sigma_p;
    const int gi = row & (B_HALF - 1);
    const float2 m2 = *(const float2*)(mup + gi * D_DIM + d0);
    const float2 s2 = *(const float2*)(sgp + gi * D_DIM + d0);
    float var0 = s2.x * s2.x, inv0 = 1.0f / var0, vm0 = var0 + m2.x * m2.x;
    float var1 = s2.y * s2.y, inv1 = 1.0f / var1, vm1 = var1 + m2.y * m2.y;
    size_t base = (size_t)row * ROWB;
    *(short*)(Gf8 + base + 0   + d0) = pk8(inv0, inv1);
    *(short*)(Gf8 + base + 128 + d0) = pk8(vm0, vm1);
    *(short*)(Gf8 + base + 256 + d0) = pk8(SQ2 * m2.x * inv0, SQ2 * m2.y * inv1);
    *(short*)(Gf8 + base + 384 + d0) = pk8(-SQ2 * m2.x, -SQ2 * m2.y);

    float av = m2.x * m2.x * inv0 + m2.y * m2.y * inv1;
#pragma unroll
    for (int x = 1; x < 64; x <<= 1) av += __shfl_xor(av, x);
    if (ln == 0) a[row] = av;
  }
}

#define GLOAD16(src, dst)                                                     \
  __builtin_amdgcn_global_load_lds(                                           \
      (const __attribute__((address_space(1))) void*)(src),                   \
      (__attribute__((address_space(3))) void*)(dst), 16, 0, 0)

// ---------------------------------------------------------------------------
// Shared body for the real kernel (STAGED=1) and the no-staging ablation
// probe (STAGED=0; stages chunk 0 only, computes 8 K-steps from it, writes
// to scratch). Structure (vmcnt/barrier cadence, ds_read, MFMA, epilogue)
// is byte-identical so the probe isolates {structure} vs {memory serving}.
// ---------------------------------------------------------------------------
template <int STAGED>
__device__ __forceinline__ void gemm_body(
    const unsigned char* __restrict__ Gf8, const float* __restrict__ a,
    float* __restrict__ lsep, float* __restrict__ pos, float to_add) {
  __shared__ char lt[3][128 * 64];   // 3 x 8 KB
  __shared__ char rt[3][128 * 64];   // 3 x 8 KB
  __shared__ float2 red[128][2];     // 2 KB

  // XCD-chunked (bid%8 -> contiguous 66-tile range), superblock-major order
  const int sb = (blockIdx.x & 7) * (NBLK / 8) + (blockIdx.x >> 3);
  int rb, cb;
  if (sb < 144) {                       // 4 diagonal superblocks, 36 each
    const int k = sb / 36;
    int t = sb - k * 36;
    int i = 0;
    while (t >= 8 - i) { t -= 8 - i; ++i; }
    rb = k * 8 + i;
    cb = k * 8 + i + t;
  } else {                              // 6 off-diagonal superblocks, 64 each
    const int o = (sb - 144) >> 6;
    const int t = (sb - 144) & 63;
    const int k1 = (o < 3) ? 0 : ((o < 5) ? 1 : 2);
    const int k2 = (o < 3) ? (o + 1) : ((o < 5) ? (o - 1) : 3);
    rb = k1 * 8 + (t >> 3);
    cb = k2 * 8 + (t & 7);
  }

  const int tid  = threadIdx.x;
  const int lane = tid & 63;
  const int wave = tid >> 6;
  const int rowBase = rb * 128, colBase = cb * 128;
  const int wr = wave >> 1, wc = wave & 1;
  const int lx = lane & 15;
  const int rq = lane >> 4;

  f32x4 acc[4][4];
#pragma unroll
  for (int m = 0; m < 4; ++m)
#pragma unroll
    for (int n = 0; n < 4; ++n) acc[m][n] = (f32x4){0.f, 0.f, 0.f, 0.f};

  // staging geometry (per GLOAD16: 16 rows x 64B = 1 KB)
  const int sr  = lane >> 2;                       // sub-row 0..15
  const int scb = (((lane & 3) ^ (sr & 3)) << 4);  // pre-swizzled src colbyte
  const char* lsrc0 = (const char*)Gf8 + (size_t)rowBase * ROWB;
  const char* rsrc0 = (const char*)Gf8 + (size_t)colBase * ROWB;

  // A reads chunk KK; B reads chunk KK^2 (feature-plane swap sigma)
#define STAGE(KK)                                                             \
  {                                                                           \
    const int b_ = (KK) % 3;                                                  \
    const char* ls_ = lsrc0 + (KK) * 64;                                      \
    const char* rs_ = rsrc0 + ((KK) ^ 2) * 64;                                \
    _Pragma("unroll")                                                         \
    for (int g = 0; g < 2; ++g) {                                             \
      const int row_ = wave * 32 + g * 16;                                    \
      GLOAD16(ls_ + (size_t)(row_ + sr) * ROWB + scb, &lt[b_][row_ * 64]);    \
      GLOAD16(rs_ + (size_t)(row_ + sr) * ROWB + scb, &rt[b_][row_ * 64]);    \
    }                                                                         \
  }

  STAGE(0)
  if (STAGED) STAGE(1)

#pragma unroll
  for (int kk = 0; kk < KSTEPS; ++kk) {
    // counted drain: stage(kk) must be landed; stage(kk+1) stays in flight
    if (kk < KSTEPS - 1) asm volatile("s_waitcnt vmcnt(4)" ::: "memory");
    else                 asm volatile("s_waitcnt vmcnt(0)" ::: "memory");
    __builtin_amdgcn_s_barrier();
    __builtin_amdgcn_sched_barrier(0);   // no reads hoisted above the barrier
    if (STAGED && kk + 2 < KSTEPS) STAGE(kk + 2)
    const int b = STAGED ? (kk % 3) : 0;
#pragma unroll
    for (int ks = 0; ks < 2; ++ks) {
      i64 af[4], bg[4];
      const int q16 = ks * 2 + (rq >> 1);      // logical 16B quad 0..3
      const int sub = (rq & 1) * 8;            // 8B half within the quad
#pragma unroll
      for (int m = 0; m < 4; ++m) {
        const int row = wr * 64 + m * 16 + lx;
        af[m] = *(const i64*)(&lt[b][row * 64 + ((q16 ^ (row & 3)) << 4) + sub]);
      }
#pragma unroll
      for (int n = 0; n < 4; ++n) {
        const int row = wc * 64 + n * 16 + lx;
        bg[n] = *(const i64*)(&rt[b][row * 64 + ((q16 ^ (row & 3)) << 4) + sub]);
      }
#pragma unroll
      for (int m = 0; m < 4; ++m)
#pragma unroll
        for (int n = 0; n < 4; ++n)
          acc[m][n] = __builtin_amdgcn_mfma_f32_16x16x32_fp8_fp8(af[m], bg[n], acc[m][n], 0, 0, 0);
    }
  }
#undef STAGE

  // ---- fused epilogue (R3/R6-proven, unchanged) ----
  const float c0 = 640.0f;   // (D/2)/T
  const float c1 = 2.5f;     // 0.25/T
  float aR[4][4];
#pragma unroll
  for (int m = 0; m < 4; ++m)
#pragma unroll
    for (int v = 0; v < 4; ++v)
      aR[m][v] = a[rowBase + wr * 64 + m * 16 + rq * 4 + v];
  float aC[4];
#pragma unroll
  for (int n = 0; n < 4; ++n) aC[n] = a[colBase + wc * 64 + n * 16 + lx];

  // pass 1: acc -> S (diag -> -inf; positive logit += to_add, pos[] writes)
#pragma unroll
  for (int m = 0; m < 4; ++m)
#pragma unroll
    for (int n = 0; n < 4; ++n)
#pragma unroll
      for (int v = 0; v < 4; ++v) {
        int grow = rowBase + wr * 64 + m * 16 + rq * 4 + v;
        int gcol = colBase + wc * 64 + n * 16 + lx;
        float S = c0 - c1 * (acc[m][n][v] + aR[m][v] + aC[n]);
        if (gcol == grow) {
          S = -INFINITY;
        } else if (gcol == (grow ^ B_HALF)) {
          S += to_add;
          pos[grow] = S;   // S symmetric: also row gcol's positive
          pos[gcol] = S;
        }
        acc[m][n][v] = S;
      }

  // pass 2: row partials -> lsep[row][cb]
#pragma unroll
  for (int m = 0; m < 4; ++m)
#pragma unroll
    for (int v = 0; v < 4; ++v) {
      float pm = -INFINITY;
#pragma unroll
      for (int n = 0; n < 4; ++n) pm = fmaxf(pm, acc[m][n][v]);
#pragma unroll
      for (int x = 1; x < 16; x <<= 1) pm = fmaxf(pm, __shfl_xor(pm, x));
      float ps = 0.f;
#pragma unroll
      for (int n = 0; n < 4; ++n) ps += __expf(acc[m][n][v] - pm);
#pragma unroll
      for (int x = 1; x < 16; x <<= 1) ps += __shfl_xor(ps, x);
      if (lx == 0) red[wr * 64 + m * 16 + rq * 4 + v][wc] = make_float2(pm, ps);
    }
  __syncthreads();
  if (tid < 128) {
    float2 p0 = red[tid][0], p1 = red[tid][1];
    float M = fmaxf(p0.x, p1.x);
    float S = p0.y * __expf(p0.x - M) + p1.y * __expf(p1.x - M);
    lsep[(size_t)(rowBase + tid) * NGRP + cb] = M + logf(S);
  }

  // pass 3: column partials -> lsep[col][rb]  (off-diagonal tiles only)
  if (rb != cb) {
    __syncthreads();
#pragma unroll
    for (int n = 0; n < 4; ++n) {
      float cm = -INFINITY;
#pragma unroll
      for (int m = 0; m < 4; ++m)
#pragma unroll
        for (int v = 0; v < 4; ++v) cm = fmaxf(cm, acc[m][n][v]);
      cm = fmaxf(cm, __shfl_xor(cm, 16));
      cm = fmaxf(cm, __shfl_xor(cm, 32));
      float cs = 0.f;
#pragma unroll
      for (int m = 0; m < 4; ++m)
#pragma unroll
        for (int v = 0; v < 4; ++v) cs += __expf(acc[m][n][v] - cm);
      cs += __shfl_xor(cs, 16);
      cs += __shfl_xor(cs, 32);
      if (lane < 16) red[wc * 64 + n * 16 + lane][wr] = make_float2(cm, cs);
    }
    __syncthreads();
    if (tid < 128) {
      float2 p0 = red[tid][0], p1 = red[tid][1];
      float M = fmaxf(p0.x, p1.x);
      float S = p0.y * __expf(p0.x - M) + p1.y * __expf(p1.x - M);
      lsep[(size_t)(colBase + tid) * NGRP + rb] = M + logf(S);
    }
  }
}

__global__ __launch_bounds__(256, 3) void gemm_lse(
    const unsigned char* __restrict__ Gf8, const float* __restrict__ a,
    float* __restrict__ lsep, float* __restrict__ pos, float to_add) {
  gemm_body<1>(Gf8, a, lsep, pos, to_add);
}

// ablation probe: identical structure, no steady-state staging; scratch out
__global__ __launch_bounds__(256, 3) void gemm_nostage(
    const unsigned char* __restrict__ Gf8, const float* __restrict__ a,
    float* __restrict__ lsep2, float* __restrict__ pos2, float to_add) {
  gemm_body<0>(Gf8, a, lsep2, pos2, to_add);
}

// ---------------------------------------------------------------------------
// P2+P3: 16 blocks x 256 thr; last finisher sums 16 partials in fixed order
// and resets the counter (R6-proven).
// ---------------------------------------------------------------------------
__global__ __launch_bounds__(256) void reduce_final(
    const float* __restrict__ lsep, const float* __restrict__ pos,
    float* __restrict__ partial, float* __restrict__ out) {
  const int tid = threadIdx.x;
  const int row = blockIdx.x * 256 + tid;
  const float* lp = lsep + (size_t)row * NGRP;
  float M = lp[0];
#pragma unroll
  for (int k = 1; k < NGRP; ++k) M = fmaxf(M, lp[k]);
  float s = 0.f;
#pragma unroll
  for (int k = 0; k < NGRP; ++k) s += __expf(lp[k] - M);
  float contrib = (M + logf(s)) - pos[row];

  __shared__ float fr[256];
  fr[tid] = contrib;
  __syncthreads();
#pragma unroll
  for (int off = 128; off > 0; off >>= 1) {
    if (tid < off) fr[tid] += fr[tid + off];
    __syncthreads();
  }
  if (tid == 0) {
    partial[blockIdx.x] = fr[0];
    unsigned v = __hip_atomic_fetch_add(&red_done, 1u, __ATOMIC_ACQ_REL,
                                        __HIP_MEMORY_SCOPE_AGENT);
    if (v == 15u) {
      float tot = 0.f;
      for (int k = 0; k < 16; ++k) tot += partial[k];
      out[0] = tot * (1.0f / 4096.0f);
      __hip_atomic_store(&red_done, 0u, __ATOMIC_RELAXED,
                         __HIP_MEMORY_SCOPE_AGENT);
    }
  }
}

// ===========================================================================
extern "C" void kernel_launch(void* const* d_in, const int* in_sizes, int n_in,
                              void* d_out, int out_size, void* d_ws, size_t ws_size,
                              hipStream_t stream) {
  const float* mu_x    = (const float*)d_in[1];
  const float* sigma_x = (const float*)d_in[2];
  const float* mu_p    = (const float*)d_in[3];
  const float* sigma_p = (const float*)d_in[4];
  float* out = (float*)d_out;

  float to_add = (float)(-log((4095.0 - 1.0 / 5.0) / 4094.0));

  const size_t featB = (size_t)N_TOT * ROWB;        // 2 MB fp8 features
  char* ws = (char*)d_ws;
  unsigned char* Gf8 = (unsigned char*)(ws);
  size_t off = featB;
  float* a       = (float*)(ws + off); off += 16384;
  float* lsep    = (float*)(ws + off); off += 524288;
  float* pos     = (float*)(ws + off); off += 16384;
  float* partial = (float*)(ws + off); off += 16384;
  float* lsep2   = (float*)(ws + off); off += 524288;   // probe scratch
  float* pos2    = (float*)(ws + off); off += 16384;

  prep_feat<<<dim3(256), dim3(256), 0, stream>>>(mu_x, sigma_x, mu_p, sigma_p,
                                                 Gf8, a);
  gemm_lse<<<dim3(NBLK), dim3(256), 0, stream>>>(Gf8, a, lsep, pos, to_add);
  reduce_final<<<dim3(16), dim3(256), 0, stream>>>(lsep, pos, partial, out);
  // ablation probe (after the real pipeline; output never validated)
  gemm_nostage<<<dim3(NBLK), dim3(256), 0, stream>>>(Gf8, a, lsep2, pos2, to_add);
}

// Round 17
// 46.906 us; speedup vs baseline: 1.2745x; 1.2745x over previous
//
#include <hip/hip_runtime.h>
#include <hip/hip_bf16.h>
#include <math.h>

typedef float f32x4 __attribute__((ext_vector_type(4)));
typedef long  i64;

#define B_HALF 2048
#define N_TOT  4096
#define D_DIM  128
#define NGRP   32
#define NBLK   528      // triangular 32x32 tile grid (528 % 8 == 0)
#define NCHUNK 8        // K chunks of 64 fp8 bytes
#define CHUNKB (N_TOT * 64)   // 256 KB per chunk plane (chunk-major layout)

// winner counter for the final reduction (zero at load; winner resets ->
// deterministic across graph replays; increment-only, nobody spins).
__device__ unsigned red_done;

// pack two floats -> two OCP e4m3 fp8 (low byte = first arg, RNE)
__device__ __forceinline__ short pk8(float x, float y) {
  return (short)__builtin_amdgcn_cvt_pk_fp8_f32(x, y, 0, false);
}

// ---------------------------------------------------------------------------
// P0: fp8-e4m3 features, CHUNK-MAJOR: GfT[c][row][64B], c = 0..7.
// Logical row bytes [0..511] = planes [inv, var+mu2, sqrt2*mu*inv,
// -sqrt2*mu] x 128B; plane p -> chunks 2p, 2p+1. sigma (plane swap
// 0<->1, 2<->3) == chunk index c ^ 2 (checked: 0<->2, 1<->3, 4<->6, 5<->7).
// a_i = sum_d mu^2*inv stays exact f32.
// ---------------------------------------------------------------------------
__global__ __launch_bounds__(256) void prep_feat(
    const float* __restrict__ mu_x, const float* __restrict__ sigma_x,
    const float* __restrict__ mu_p, const float* __restrict__ sigma_p,
    unsigned char* __restrict__ GfT, float* __restrict__ a) {
  const int tid = threadIdx.x;
  const int wv = tid >> 6;
  const int ln = tid & 63;
  const int d0 = ln * 2;
  const int hi = d0 >> 6;          // which chunk of the plane pair
  const int off = d0 & 63;         // byte offset within chunk
  const float SQ2 = 1.41421356237309515f;
#pragma unroll
  for (int rr = 0; rr < 16; rr += 4) {
    const int row = blockIdx.x * 16 + rr + wv;
    const float* mup = (row < B_HALF) ? mu_x : mu_p;
    const float* sgp = (row < B_HALF) ? sigma_x : sigma_p;
    const int gi = row & (B_HALF - 1);
    const float2 m2 = *(const float2*)(mup + gi * D_DIM + d0);
    const float2 s2 = *(const float2*)(sgp + gi * D_DIM + d0);
    float var0 = s2.x * s2.x, inv0 = 1.0f / var0, vm0 = var0 + m2.x * m2.x;
    float var1 = s2.y * s2.y, inv1 = 1.0f / var1, vm1 = var1 + m2.y * m2.y;
    const size_t rb = (size_t)row * 64 + off;
    *(short*)(GfT + (size_t)(0 + hi) * CHUNKB + rb) = pk8(inv0, inv1);
    *(short*)(GfT + (size_t)(2 + hi) * CHUNKB + rb) = pk8(vm0, vm1);
    *(short*)(GfT + (size_t)(4 + hi) * CHUNKB + rb) = pk8(SQ2 * m2.x * inv0, SQ2 * m2.y * inv1);
    *(short*)(GfT + (size_t)(6 + hi) * CHUNKB + rb) = pk8(-SQ2 * m2.x, -SQ2 * m2.y);

    float av = m2.x * m2.x * inv0 + m2.y * m2.y * inv1;
#pragma unroll
    for (int x = 1; x < 64; x <<= 1) av += __shfl_xor(av, x);
    if (ln == 0) a[row] = av;
  }
}

// ---------------------------------------------------------------------------
// P1: BARRIER-FREE dataflow GEMM. 128x128 tile, 4 waves (each 64x64).
// No LDS staging, no s_barrier / vmcnt asm / sched_barrier in the K-loop:
// each wave loads its MFMA fragments straight from the chunk-major Gf8
// (L2-resident 2 MB; wave-pair duplicates hit L1). Fragment address =
// SGPR chunk base + one per-lane VGPR offset + 13-bit imm -> the compiler
// is free to software-pipeline all 8 chunks deep. Superblock tile order
// (R12-proven, L2-local). Epilogue identical to R6..R16.
// ---------------------------------------------------------------------------
__global__ __launch_bounds__(256, 3) void gemm_lse(
    const unsigned char* __restrict__ GfT, const float* __restrict__ a,
    float* __restrict__ lsep, float* __restrict__ pos, float to_add) {
  __shared__ float2 red[128][2];     // 2 KB (epilogue only)

  // XCD-chunked (bid%8 -> contiguous 66-tile range), superblock-major order
  const int sb = (blockIdx.x & 7) * (NBLK / 8) + (blockIdx.x >> 3);
  int rb, cb;
  if (sb < 144) {                       // 4 diagonal superblocks, 36 each
    const int k = sb / 36;
    int t = sb - k * 36;
    int i = 0;
    while (t >= 8 - i) { t -= 8 - i; ++i; }
    rb = k * 8 + i;
    cb = k * 8 + i + t;
  } else {                              // 6 off-diagonal superblocks, 64 each
    const int o = (sb - 144) >> 6;
    const int t = (sb - 144) & 63;
    const int k1 = (o < 3) ? 0 : ((o < 5) ? 1 : 2);
    const int k2 = (o < 3) ? (o + 1) : ((o < 5) ? (o - 1) : 3);
    rb = k1 * 8 + (t >> 3);
    cb = k2 * 8 + (t & 7);
  }

  const int tid  = threadIdx.x;
  const int lane = tid & 63;
  const int wave = tid >> 6;
  const int rowBase = rb * 128, colBase = cb * 128;
  const int wr = wave >> 1, wc = wave & 1;
  const int lx = lane & 15;
  const int rq = lane >> 4;

  f32x4 acc[4][4];
#pragma unroll
  for (int m = 0; m < 4; ++m)
#pragma unroll
    for (int n = 0; n < 4; ++n) acc[m][n] = (f32x4){0.f, 0.f, 0.f, 0.f};

  // per-lane byte offset within a wave's contiguous 4 KB fragment window:
  // row lx (64B rows), bytes rq*8 within the ks-selected 32B half
  const int vlane = lx * 64 + rq * 8;
  const int voffA = wr * 4096 + vlane;   // wave's 64-row A window
  const int voffB = wc * 4096 + vlane;   // wave's 64-row B window

#pragma unroll
  for (int kk = 0; kk < NCHUNK; ++kk) {
    const char* Ak = (const char*)GfT + (size_t)kk * CHUNKB +
                     (size_t)rowBase * 64 + voffA;
    const char* Bk = (const char*)GfT + (size_t)(kk ^ 2) * CHUNKB +
                     (size_t)colBase * 64 + voffB;
#pragma unroll
    for (int ks = 0; ks < 2; ++ks) {
      i64 af[4], bg[4];
#pragma unroll
      for (int m = 0; m < 4; ++m)
        af[m] = *(const i64*)(Ak + m * 1024 + ks * 32);
#pragma unroll
      for (int n = 0; n < 4; ++n)
        bg[n] = *(const i64*)(Bk + n * 1024 + ks * 32);
#pragma unroll
      for (int m = 0; m < 4; ++m)
#pragma unroll
        for (int n = 0; n < 4; ++n)
          acc[m][n] = __builtin_amdgcn_mfma_f32_16x16x32_fp8_fp8(af[m], bg[n], acc[m][n], 0, 0, 0);
    }
  }

  // ---- fused epilogue (R3/R6-proven, unchanged) ----
  const float c0 = 640.0f;   // (D/2)/T
  const float c1 = 2.5f;     // 0.25/T
  float aR[4][4];
#pragma unroll
  for (int m = 0; m < 4; ++m)
#pragma unroll
    for (int v = 0; v < 4; ++v)
      aR[m][v] = a[rowBase + wr * 64 + m * 16 + rq * 4 + v];
  float aC[4];
#pragma unroll
  for (int n = 0; n < 4; ++n) aC[n] = a[colBase + wc * 64 + n * 16 + lx];

  // pass 1: acc -> S (diag -> -inf; positive logit += to_add, pos[] writes)
#pragma unroll
  for (int m = 0; m < 4; ++m)
#pragma unroll
    for (int n = 0; n < 4; ++n)
#pragma unroll
      for (int v = 0; v < 4; ++v) {
        int grow = rowBase + wr * 64 + m * 16 + rq * 4 + v;
        int gcol = colBase + wc * 64 + n * 16 + lx;
        float S = c0 - c1 * (acc[m][n][v] + aR[m][v] + aC[n]);
        if (gcol == grow) {
          S = -INFINITY;
        } else if (gcol == (grow ^ B_HALF)) {
          S += to_add;
          pos[grow] = S;   // S symmetric: also row gcol's positive
          pos[gcol] = S;
        }
        acc[m][n][v] = S;
      }

  // pass 2: row partials -> lsep[row][cb]
#pragma unroll
  for (int m = 0; m < 4; ++m)
#pragma unroll
    for (int v = 0; v < 4; ++v) {
      float pm = -INFINITY;
#pragma unroll
      for (int n = 0; n < 4; ++n) pm = fmaxf(pm, acc[m][n][v]);
#pragma unroll
      for (int x = 1; x < 16; x <<= 1) pm = fmaxf(pm, __shfl_xor(pm, x));
      float ps = 0.f;
#pragma unroll
      for (int n = 0; n < 4; ++n) ps += __expf(acc[m][n][v] - pm);
#pragma unroll
      for (int x = 1; x < 16; x <<= 1) ps += __shfl_xor(ps, x);
      if (lx == 0) red[wr * 64 + m * 16 + rq * 4 + v][wc] = make_float2(pm, ps);
    }
  __syncthreads();
  if (tid < 128) {
    float2 p0 = red[tid][0], p1 = red[tid][1];
    float M = fmaxf(p0.x, p1.x);
    float S = p0.y * __expf(p0.x - M) + p1.y * __expf(p1.x - M);
    lsep[(size_t)(rowBase + tid) * NGRP + cb] = M + logf(S);
  }

  // pass 3: column partials -> lsep[col][rb]  (off-diagonal tiles only)
  if (rb != cb) {
    __syncthreads();
#pragma unroll
    for (int n = 0; n < 4; ++n) {
      float cm = -INFINITY;
#pragma unroll
      for (int m = 0; m < 4; ++m)
#pragma unroll
        for (int v = 0; v < 4; ++v) cm = fmaxf(cm, acc[m][n][v]);
      cm = fmaxf(cm, __shfl_xor(cm, 16));
      cm = fmaxf(cm, __shfl_xor(cm, 32));
      float cs = 0.f;
#pragma unroll
      for (int m = 0; m < 4; ++m)
#pragma unroll
        for (int v = 0; v < 4; ++v) cs += __expf(acc[m][n][v] - cm);
      cs += __shfl_xor(cs, 16);
      cs += __shfl_xor(cs, 32);
      if (lane < 16) red[wc * 64 + n * 16 + lane][wr] = make_float2(cm, cs);
    }
    __syncthreads();
    if (tid < 128) {
      float2 p0 = red[tid][0], p1 = red[tid][1];
      float M = fmaxf(p0.x, p1.x);
      float S = p0.y * __expf(p0.x - M) + p1.y * __expf(p1.x - M);
      lsep[(size_t)(colBase + tid) * NGRP + rb] = M + logf(S);
    }
  }
}

// ---------------------------------------------------------------------------
// P2+P3: 16 blocks x 256 thr; last finisher sums 16 partials in fixed order
// and resets the counter (R6-proven).
// ---------------------------------------------------------------------------
__global__ __launch_bounds__(256) void reduce_final(
    const float* __restrict__ lsep, const float* __restrict__ pos,
    float* __restrict__ partial, float* __restrict__ out) {
  const int tid = threadIdx.x;
  const int row = blockIdx.x * 256 + tid;
  const float* lp = lsep + (size_t)row * NGRP;
  float M = lp[0];
#pragma unroll
  for (int k = 1; k < NGRP; ++k) M = fmaxf(M, lp[k]);
  float s = 0.f;
#pragma unroll
  for (int k = 0; k < NGRP; ++k) s += __expf(lp[k] - M);
  float contrib = (M + logf(s)) - pos[row];

  __shared__ float fr[256];
  fr[tid] = contrib;
  __syncthreads();
#pragma unroll
  for (int off = 128; off > 0; off >>= 1) {
    if (tid < off) fr[tid] += fr[tid + off];
    __syncthreads();
  }
  if (tid == 0) {
    partial[blockIdx.x] = fr[0];
    unsigned v = __hip_atomic_fetch_add(&red_done, 1u, __ATOMIC_ACQ_REL,
                                        __HIP_MEMORY_SCOPE_AGENT);
    if (v == 15u) {
      float tot = 0.f;
      for (int k = 0; k < 16; ++k) tot += partial[k];
      out[0] = tot * (1.0f / 4096.0f);
      __hip_atomic_store(&red_done, 0u, __ATOMIC_RELAXED,
                         __HIP_MEMORY_SCOPE_AGENT);
    }
  }
}

// ===========================================================================
extern "C" void kernel_launch(void* const* d_in, const int* in_sizes, int n_in,
                              void* d_out, int out_size, void* d_ws, size_t ws_size,
                              hipStream_t stream) {
  const float* mu_x    = (const float*)d_in[1];
  const float* sigma_x = (const float*)d_in[2];
  const float* mu_p    = (const float*)d_in[3];
  const float* sigma_p = (const float*)d_in[4];
  float* out = (float*)d_out;

  float to_add = (float)(-log((4095.0 - 1.0 / 5.0) / 4094.0));

  const size_t featB = (size_t)NCHUNK * CHUNKB;     // 2 MB chunk-major fp8
  char* ws = (char*)d_ws;
  unsigned char* GfT = (unsigned char*)(ws);
  size_t off = featB;
  float* a       = (float*)(ws + off); off += 16384;
  float* lsep    = (float*)(ws + off); off += 524288;
  float* pos     = (float*)(ws + off); off += 16384;
  float* partial = (float*)(ws + off); off += 16384;

  prep_feat<<<dim3(256), dim3(256), 0, stream>>>(mu_x, sigma_x, mu_p, sigma_p,
                                                 GfT, a);
  gemm_lse<<<dim3(NBLK), dim3(256), 0, stream>>>(GfT, a, lsep, pos, to_add);
  reduce_final<<<dim3(16), dim3(256), 0, stream>>>(lsep, pos, partial, out);
}

// Round 18
// 46.686 us; speedup vs baseline: 1.2805x; 1.0047x over previous
//
#include <hip/hip_runtime.h>
#include <hip/hip_bf16.h>
#include <math.h>

typedef short bf16x8 __attribute__((ext_vector_type(8)));
typedef float f32x4 __attribute__((ext_vector_type(4)));

#define B_HALF 2048
#define N_TOT  4096
#define D_DIM  128
#define K_DIM  512
#define NGRP   16
#define NBLK   136    // triangular 16x16 tile grid of 256^2 tiles (136%8==0)

// winner counter for the final reduction (zero at load; winner resets ->
// deterministic across graph replays; increment-only, nobody spins).
__device__ unsigned red_done;

// ---------------------------------------------------------------------------
// P0: unified bf16 features G + a[] (R12-proven, NT stores).
// G_i = [inv, var+mu2, sqrt2*mu*inv, -sqrt2*mu] (elem planes of 128).
// Symmetric KL sum = sum_k G_i[k]*G_j[sigma(k)]; with 128-BYTE chunks
// (64 bf16), planes = chunk pairs -> sigma = chunk index ^ 2.
// a_i = sum_d mu^2 * inv
// ---------------------------------------------------------------------------
__global__ __launch_bounds__(256) void prep_feat(
    const float* __restrict__ mu_x, const float* __restrict__ sigma_x,
    const float* __restrict__ mu_p, const float* __restrict__ sigma_p,
    __hip_bfloat16* __restrict__ Gf, float* __restrict__ a) {
  const int tid = threadIdx.x;
  const int wv = tid >> 6;
  const int ln = tid & 63;
  const int d0 = ln * 2;
  const float SQ2 = 1.41421356237309515f;
#pragma unroll
  for (int rr = 0; rr < 16; rr += 4) {
    const int row = blockIdx.x * 16 + rr + wv;
    const float* mup = (row < B_HALF) ? mu_x : mu_p;
    const float* sgp = (row < B_HALF) ? sigma_x : sigma_p;
    const int gi = row & (B_HALF - 1);
    const float2 m2 = *(const float2*)(mup + gi * D_DIM + d0);
    const float2 s2 = *(const float2*)(sgp + gi * D_DIM + d0);
    float var0 = s2.x * s2.x, inv0 = 1.0f / var0, vm0 = var0 + m2.x * m2.x;
    float var1 = s2.y * s2.y, inv1 = 1.0f / var1, vm1 = var1 + m2.y * m2.y;
    size_t base = (size_t)row * K_DIM;
    __hip_bfloat162 h;
    unsigned ub;
#define PK2(OFF, X, Y)                                                        \
    h.x = __float2bfloat16(X); h.y = __float2bfloat16(Y);                     \
    __builtin_memcpy(&ub, &h, 4);                                             \
    __builtin_nontemporal_store(ub, (unsigned*)(Gf + base + (OFF) + d0));
    PK2(0,   inv0, inv1)
    PK2(128, vm0, vm1)
    PK2(256, SQ2 * m2.x * inv0, SQ2 * m2.y * inv1)
    PK2(384, -SQ2 * m2.x, -SQ2 * m2.y)
#undef PK2
    float av = m2.x * m2.x * inv0 + m2.y * m2.y * inv1;
#pragma unroll
    for (int x = 1; x < 64; x <<= 1) av += __shfl_xor(av, x);
    if (ln == 0) __builtin_nontemporal_store(av, &a[row]);
  }
}

#define GLOAD16(src, dst)                                                     \
  __builtin_amdgcn_global_load_lds(                                           \
      (const __attribute__((address_space(1))) void*)(src),                   \
      (__attribute__((address_space(3))) void*)(dst), 16, 0, 0)

// ---------------------------------------------------------------------------
// P1: 256x256 tile, 8 waves (2x4), ONE block per CU (131 KB LDS), single
// occupancy round (136 blocks <= 256 CUs -> wall = one block's latency).
// BK=64 bf16 = 128 B chunks; double-buffered 2x(A 32K + B 32K); counted
// vmcnt(8) (next stage's 8 loads stay in flight); 8 phases x 2 barriers.
// Swizzle (rule #21 both-sides): LDS[row][pq*16] = G[row][chunk][pq ^
// (row&7)]; read logical lq at phys lq^(row&7); b128 reads -> 2-way free.
// ---------------------------------------------------------------------------
__global__ __launch_bounds__(512, 2) void gemm_lse(
    const __hip_bfloat16* __restrict__ Gf, const float* __restrict__ a,
    float* __restrict__ lsep, float* __restrict__ pos, float to_add) {
  __shared__ char smem[2][65536];   // [buf][A 32K | B 32K] = 128 KB

  // XCD-chunked (bid%8 -> contiguous 17-tile range), triangular 16x16
  const int sb = (blockIdx.x & 7) * (NBLK / 8) + (blockIdx.x >> 3);
  int t = sb, rb = 0;
  while (t >= 16 - rb) { t -= 16 - rb; ++rb; }
  const int cb = rb + t;

  const int tid  = threadIdx.x;
  const int lane = tid & 63;
  const int wave = tid >> 6;        // 0..7
  const int wr = wave >> 2;         // 0..1 : 128-row half
  const int wc = wave & 3;          // 0..3 : 64-col quarter
  const int lx = lane & 15;
  const int rq = lane >> 4;
  const int rowBase = rb * 256, colBase = cb * 256;

  f32x4 acc[8][4];
#pragma unroll
  for (int m = 0; m < 8; ++m)
#pragma unroll
    for (int n = 0; n < 4; ++n) acc[m][n] = (f32x4){0.f, 0.f, 0.f, 0.f};

  const int srow = lane >> 3;       // row within 8-row/1KB GLOAD group
  const char* gb = (const char*)Gf;

  // A reads chunk KK; B reads chunk KK^2 (feature-plane swap sigma)
#define STAGE(KK)                                                             \
  {                                                                           \
    const int b_ = (KK) & 1;                                                  \
    _Pragma("unroll")                                                         \
    for (int g = 0; g < 4; ++g) {                                             \
      const int br   = wave * 32 + g * 8;                                     \
      const int row_ = br + srow;                                             \
      const int sq   = ((lane & 7) ^ (row_ & 7)) << 4;                        \
      GLOAD16(gb + (size_t)(rowBase + row_) * 1024 + (KK) * 128 + sq,         \
              &smem[b_][br * 128]);                                           \
      GLOAD16(gb + (size_t)(colBase + row_) * 1024 + ((KK) ^ 2) * 128 + sq,   \
              &smem[b_][32768 + br * 128]);                                   \
    }                                                                         \
  }

  STAGE(0)
  STAGE(1)

#pragma unroll
  for (int kk = 0; kk < 8; ++kk) {
    // counted drain: stage kk landed (8/thread of stage kk+1 in flight)
    if (kk < 7) asm volatile("s_waitcnt vmcnt(8)" ::: "memory");
    else        asm volatile("s_waitcnt vmcnt(0)" ::: "memory");
    __builtin_amdgcn_s_barrier();
    __builtin_amdgcn_sched_barrier(0);   // no reads hoisted above the barrier
    const int b = kk & 1;
#pragma unroll
    for (int ks = 0; ks < 2; ++ks) {
      bf16x8 af[8], bg[4];
      const int lq = ks * 4 + rq;        // logical 16B quad 0..7
#pragma unroll
      for (int m = 0; m < 8; ++m) {
        const int row = wr * 128 + m * 16 + lx;
        af[m] = *(const bf16x8*)&smem[b][row * 128 + ((lq ^ (row & 7)) << 4)];
      }
#pragma unroll
      for (int n = 0; n < 4; ++n) {
        const int row = wc * 64 + n * 16 + lx;
        bg[n] = *(const bf16x8*)&smem[b][32768 + row * 128 + ((lq ^ (row & 7)) << 4)];
      }
#pragma unroll
      for (int m = 0; m < 8; ++m)
#pragma unroll
        for (int n = 0; n < 4; ++n)
          acc[m][n] = __builtin_amdgcn_mfma_f32_16x16x32_bf16(af[m], bg[n], acc[m][n], 0, 0, 0);
    }
    __builtin_amdgcn_s_barrier();        // reads of buf b done -> writable
    if (kk + 2 < 8) STAGE(kk + 2)
  }
#undef STAGE

  __syncthreads();   // staging buffers dead; reuse as epilogue scratch
  float2 (*red)[4] = (float2 (*)[4])&smem[0][0];   // [256][4] = 8 KB

  // ---- fused epilogue (R3/R6-proven logic, 256-tile shape) ----
  const float c0 = 640.0f;   // (D/2)/T
  const float c1 = 2.5f;     // 0.25/T
  float aR[8][4];
#pragma unroll
  for (int m = 0; m < 8; ++m)
#pragma unroll
    for (int v = 0; v < 4; ++v)
      aR[m][v] = a[rowBase + wr * 128 + m * 16 + rq * 4 + v];
  float aC[4];
#pragma unroll
  for (int n = 0; n < 4; ++n) aC[n] = a[colBase + wc * 64 + n * 16 + lx];

  // pass 1: acc -> S (diag -> -inf; positive logit += to_add, pos[] writes)
#pragma unroll
  for (int m = 0; m < 8; ++m)
#pragma unroll
    for (int n = 0; n < 4; ++n)
#pragma unroll
      for (int v = 0; v < 4; ++v) {
        int grow = rowBase + wr * 128 + m * 16 + rq * 4 + v;
        int gcol = colBase + wc * 64 + n * 16 + lx;
        float S = c0 - c1 * (acc[m][n][v] + aR[m][v] + aC[n]);
        if (gcol == grow) {
          S = -INFINITY;
        } else if (gcol == (grow ^ B_HALF)) {
          S += to_add;
          pos[grow] = S;   // S symmetric: also row gcol's positive
          pos[gcol] = S;
        }
        acc[m][n][v] = S;
      }

  // pass 2: row partials (over this tile's 256 cols) -> lsep[row][cb]
#pragma unroll
  for (int m = 0; m < 8; ++m)
#pragma unroll
    for (int v = 0; v < 4; ++v) {
      float pm = -INFINITY;
#pragma unroll
      for (int n = 0; n < 4; ++n) pm = fmaxf(pm, acc[m][n][v]);
#pragma unroll
      for (int x = 1; x < 16; x <<= 1) pm = fmaxf(pm, __shfl_xor(pm, x));
      float ps = 0.f;
#pragma unroll
      for (int n = 0; n < 4; ++n) ps += __expf(acc[m][n][v] - pm);
#pragma unroll
      for (int x = 1; x < 16; x <<= 1) ps += __shfl_xor(ps, x);
      if (lx == 0) red[wr * 128 + m * 16 + rq * 4 + v][wc] = make_float2(pm, ps);
    }
  __syncthreads();
  if (tid < 256) {
    float M = -INFINITY;
#pragma unroll
    for (int g = 0; g < 4; ++g) M = fmaxf(M, red[tid][g].x);
    float S = 0.f;
#pragma unroll
    for (int g = 0; g < 4; ++g) S += red[tid][g].y * __expf(red[tid][g].x - M);
    lsep[(size_t)(rowBase + tid) * NGRP + cb] = M + logf(S);
  }

  // pass 3: column partials -> lsep[col][rb]  (off-diagonal tiles only)
  if (rb != cb) {
    __syncthreads();
#pragma unroll
    for (int n = 0; n < 4; ++n) {
      float cm = -INFINITY;
#pragma unroll
      for (int m = 0; m < 8; ++m)
#pragma unroll
        for (int v = 0; v < 4; ++v) cm = fmaxf(cm, acc[m][n][v]);
      cm = fmaxf(cm, __shfl_xor(cm, 16));
      cm = fmaxf(cm, __shfl_xor(cm, 32));
      float cs = 0.f;
#pragma unroll
      for (int m = 0; m < 8; ++m)
#pragma unroll
        for (int v = 0; v < 4; ++v) cs += __expf(acc[m][n][v] - cm);
      cs += __shfl_xor(cs, 16);
      cs += __shfl_xor(cs, 32);
      if (lane < 16) red[wc * 64 + n * 16 + lane][wr] = make_float2(cm, cs);
    }
    __syncthreads();
    if (tid < 256) {
      float2 p0 = red[tid][0], p1 = red[tid][1];
      float M = fmaxf(p0.x, p1.x);
      float S = p0.y * __expf(p0.x - M) + p1.y * __expf(p1.x - M);
      lsep[(size_t)(colBase + tid) * NGRP + rb] = M + logf(S);
    }
  }
}

// ---------------------------------------------------------------------------
// P2+P3: 16 blocks x 256 thr; last finisher sums 16 partials in fixed order
// and resets the counter (R6-proven). NGRP = 16 column groups now.
// ---------------------------------------------------------------------------
__global__ __launch_bounds__(256) void reduce_final(
    const float* __restrict__ lsep, const float* __restrict__ pos,
    float* __restrict__ partial, float* __restrict__ out) {
  const int tid = threadIdx.x;
  const int row = blockIdx.x * 256 + tid;
  const float* lp = lsep + (size_t)row * NGRP;
  float M = lp[0];
#pragma unroll
  for (int k = 1; k < NGRP; ++k) M = fmaxf(M, lp[k]);
  float s = 0.f;
#pragma unroll
  for (int k = 0; k < NGRP; ++k) s += __expf(lp[k] - M);
  float contrib = (M + logf(s)) - pos[row];

  __shared__ float fr[256];
  fr[tid] = contrib;
  __syncthreads();
#pragma unroll
  for (int off = 128; off > 0; off >>= 1) {
    if (tid < off) fr[tid] += fr[tid + off];
    __syncthreads();
  }
  if (tid == 0) {
    partial[blockIdx.x] = fr[0];
    unsigned v = __hip_atomic_fetch_add(&red_done, 1u, __ATOMIC_ACQ_REL,
                                        __HIP_MEMORY_SCOPE_AGENT);
    if (v == 15u) {
      float tot = 0.f;
      for (int k = 0; k < 16; ++k) tot += partial[k];
      out[0] = tot * (1.0f / 4096.0f);
      __hip_atomic_store(&red_done, 0u, __ATOMIC_RELAXED,
                         __HIP_MEMORY_SCOPE_AGENT);
    }
  }
}

// ===========================================================================
extern "C" void kernel_launch(void* const* d_in, const int* in_sizes, int n_in,
                              void* d_out, int out_size, void* d_ws, size_t ws_size,
                              hipStream_t stream) {
  const float* mu_x    = (const float*)d_in[1];
  const float* sigma_x = (const float*)d_in[2];
  const float* mu_p    = (const float*)d_in[3];
  const float* sigma_p = (const float*)d_in[4];
  float* out = (float*)d_out;

  float to_add = (float)(-log((4095.0 - 1.0 / 5.0) / 4094.0));

  const size_t featB = (size_t)N_TOT * K_DIM * 2;   // 4 MB bf16 features
  char* ws = (char*)d_ws;
  __hip_bfloat16* Gf = (__hip_bfloat16*)(ws);
  size_t off = featB;
  float* a       = (float*)(ws + off); off += 16384;
  float* lsep    = (float*)(ws + off); off += (size_t)N_TOT * NGRP * 4;  // 256 KB
  float* pos     = (float*)(ws + off); off += 16384;
  float* partial = (float*)(ws + off); off += 16384;

  prep_feat<<<dim3(256), dim3(256), 0, stream>>>(mu_x, sigma_x, mu_p, sigma_p,
                                                 Gf, a);
  gemm_lse<<<dim3(NBLK), dim3(512), 0, stream>>>(Gf, a, lsep, pos, to_add);
  reduce_final<<<dim3(16), dim3(256), 0, stream>>>(lsep, pos, partial, out);
}

// Round 19
// 37.062 us; speedup vs baseline: 1.6130x; 1.2597x over previous
//
#include <hip/hip_runtime.h>
#include <hip/hip_bf16.h>
#include <math.h>

typedef float f32x4 __attribute__((ext_vector_type(4)));
typedef long  i64;

#define B_HALF 2048
#define N_TOT  4096
#define D_DIM  128
#define NGRP   32
#define NBLK   528   // triangular 32x32 tile grid (528 % 8 == 0)
#define KSTEPS 8     // K chunks of 64 (fp8: 64 B per row-chunk)
#define ROWB   512   // Gf8 row pitch in bytes (512 fp8 features)

// winner counter for the final reduction (zero at load; winner resets ->
// deterministic across graph replays; increment-only, nobody spins).
__device__ unsigned red_done;

// pack two floats -> two OCP e4m3 fp8 (low byte = first arg, RNE)
__device__ __forceinline__ short pk8(float x, float y) {
  return (short)__builtin_amdgcn_cvt_pk_fp8_f32(x, y, 0, false);
}

// ---------------------------------------------------------------------------
// P0: fp8-e4m3 features G + f32 a[].
// G_i = [inv, var+mu2, sqrt2*mu*inv, -sqrt2*mu]  (planes of 128 bytes)
// Symmetric KL sum = sum_k G_i[k]*G_j[sigma(k)], sigma swaps planes 0<->1,
// 2<->3 -> with 64 B chunks that is chunk index kk ^ 2.
// a_i = sum_d mu^2 * inv  (kept exact in f32 -> only `dot` sees fp8 error)
// ---------------------------------------------------------------------------
__global__ __launch_bounds__(256) void prep_feat(
    const float* __restrict__ mu_x, const float* __restrict__ sigma_x,
    const float* __restrict__ mu_p, const float* __restrict__ sigma_p,
    unsigned char* __restrict__ Gf8, float* __restrict__ a) {
  const int tid = threadIdx.x;
  const int wv = tid >> 6;
  const int ln = tid & 63;
  const int d0 = ln * 2;
  const float SQ2 = 1.41421356237309515f;
#pragma unroll
  for (int rr = 0; rr < 16; rr += 4) {
    const int row = blockIdx.x * 16 + rr + wv;
    const float* mup = (row < B_HALF) ? mu_x : mu_p;
    const float* sgp = (row < B_HALF) ? sigma_x : sigma_p;
    const int gi = row & (B_HALF - 1);
    const float2 m2 = *(const float2*)(mup + gi * D_DIM + d0);
    const float2 s2 = *(const float2*)(sgp + gi * D_DIM + d0);
    float var0 = s2.x * s2.x, inv0 = 1.0f / var0, vm0 = var0 + m2.x * m2.x;
    float var1 = s2.y * s2.y, inv1 = 1.0f / var1, vm1 = var1 + m2.y * m2.y;
    size_t base = (size_t)row * ROWB;
    *(short*)(Gf8 + base + 0   + d0) = pk8(inv0, inv1);
    *(short*)(Gf8 + base + 128 + d0) = pk8(vm0, vm1);
    *(short*)(Gf8 + base + 256 + d0) = pk8(SQ2 * m2.x * inv0, SQ2 * m2.y * inv1);
    *(short*)(Gf8 + base + 384 + d0) = pk8(-SQ2 * m2.x, -SQ2 * m2.y);

    float av = m2.x * m2.x * inv0 + m2.y * m2.y * inv1;
#pragma unroll
    for (int x = 1; x < 64; x <<= 1) av += __shfl_xor(av, x);
    if (ln == 0) a[row] = av;
  }
}

#define GLOAD16(src, dst)                                                     \
  __builtin_amdgcn_global_load_lds(                                           \
      (const __attribute__((address_space(1))) void*)(src),                   \
      (__attribute__((address_space(3))) void*)(dst), 16, 0, 0)

// ---------------------------------------------------------------------------
// P1: triangular 128x128 MFMA tile, fp8 operands. BK=64 fp8 -> 64 B rows:
// 2 GLOAD16 per side per thread, 16 B XOR swizzle q^(row&3), ring-of-3
// LDS, counted vmcnt(4); 8 K-steps. Superblock schedule for L2 residency.
// Fragment: mfma_f32_16x16x32_fp8_fp8, 8 fp8/lane (i64), same lane map as
// bf16 16x16x32; per K-step two ks sub-steps (k 0..31 / 32..63).
// (Best measured configuration of the session: R14 = 37.2 us.)
// ---------------------------------------------------------------------------
__global__ __launch_bounds__(256, 3) void gemm_lse(
    const unsigned char* __restrict__ Gf8, const float* __restrict__ a,
    float* __restrict__ lsep, float* __restrict__ pos, float to_add) {
  __shared__ char lt[3][128 * 64];   // 3 x 8 KB
  __shared__ char rt[3][128 * 64];   // 3 x 8 KB
  __shared__ float2 red[128][2];     // 2 KB

  // XCD-chunked (bid%8 -> contiguous 66-tile range), superblock-major order
  const int sb = (blockIdx.x & 7) * (NBLK / 8) + (blockIdx.x >> 3);
  int rb, cb;
  if (sb < 144) {                       // 4 diagonal superblocks, 36 each
    const int k = sb / 36;
    int t = sb - k * 36;
    int i = 0;
    while (t >= 8 - i) { t -= 8 - i; ++i; }
    rb = k * 8 + i;
    cb = k * 8 + i + t;
  } else {                              // 6 off-diagonal superblocks, 64 each
    const int o = (sb - 144) >> 6;
    const int t = (sb - 144) & 63;
    const int k1 = (o < 3) ? 0 : ((o < 5) ? 1 : 2);
    const int k2 = (o < 3) ? (o + 1) : ((o < 5) ? (o - 1) : 3);
    rb = k1 * 8 + (t >> 3);
    cb = k2 * 8 + (t & 7);
  }

  const int tid  = threadIdx.x;
  const int lane = tid & 63;
  const int wave = tid >> 6;
  const int rowBase = rb * 128, colBase = cb * 128;
  const int wr = wave >> 1, wc = wave & 1;
  const int lx = lane & 15;
  const int rq = lane >> 4;

  f32x4 acc[4][4];
#pragma unroll
  for (int m = 0; m < 4; ++m)
#pragma unroll
    for (int n = 0; n < 4; ++n) acc[m][n] = (f32x4){0.f, 0.f, 0.f, 0.f};

  // staging geometry (per GLOAD16: 16 rows x 64B = 1 KB)
  const int sr  = lane >> 2;                       // sub-row 0..15
  const int scb = (((lane & 3) ^ (sr & 3)) << 4);  // pre-swizzled src colbyte
  const char* lsrc0 = (const char*)Gf8 + (size_t)rowBase * ROWB;
  const char* rsrc0 = (const char*)Gf8 + (size_t)colBase * ROWB;

  // A reads chunk KK; B reads chunk KK^2 (feature-plane swap sigma)
#define STAGE(KK)                                                             \
  {                                                                           \
    const int b_ = (KK) % 3;                                                  \
    const char* ls_ = lsrc0 + (KK) * 64;                                      \
    const char* rs_ = rsrc0 + ((KK) ^ 2) * 64;                                \
    _Pragma("unroll")                                                         \
    for (int g = 0; g < 2; ++g) {                                             \
      const int row_ = wave * 32 + g * 16;                                    \
      GLOAD16(ls_ + (size_t)(row_ + sr) * ROWB + scb, &lt[b_][row_ * 64]);    \
      GLOAD16(rs_ + (size_t)(row_ + sr) * ROWB + scb, &rt[b_][row_ * 64]);    \
    }                                                                         \
  }

  STAGE(0)
  STAGE(1)

#pragma unroll
  for (int kk = 0; kk < KSTEPS; ++kk) {
    // counted drain: stage(kk) must be landed; stage(kk+1) stays in flight
    if (kk < KSTEPS - 1) asm volatile("s_waitcnt vmcnt(4)" ::: "memory");
    else                 asm volatile("s_waitcnt vmcnt(0)" ::: "memory");
    __builtin_amdgcn_s_barrier();
    __builtin_amdgcn_sched_barrier(0);   // no reads hoisted above the barrier
    if (kk + 2 < KSTEPS) STAGE(kk + 2)   // into buf (kk+2)%3 == (kk-1)%3: free
    const int b = kk % 3;
#pragma unroll
    for (int ks = 0; ks < 2; ++ks) {
      i64 af[4], bg[4];
      const int q16 = ks * 2 + (rq >> 1);      // logical 16B quad 0..3
      const int sub = (rq & 1) * 8;            // 8B half within the quad
#pragma unroll
      for (int m = 0; m < 4; ++m) {
        const int row = wr * 64 + m * 16 + lx;
        af[m] = *(const i64*)(&lt[b][row * 64 + ((q16 ^ (row & 3)) << 4) + sub]);
      }
#pragma unroll
      for (int n = 0; n < 4; ++n) {
        const int row = wc * 64 + n * 16 + lx;
        bg[n] = *(const i64*)(&rt[b][row * 64 + ((q16 ^ (row & 3)) << 4) + sub]);
      }
#pragma unroll
      for (int m = 0; m < 4; ++m)
#pragma unroll
        for (int n = 0; n < 4; ++n)
          acc[m][n] = __builtin_amdgcn_mfma_f32_16x16x32_fp8_fp8(af[m], bg[n], acc[m][n], 0, 0, 0);
    }
  }
#undef STAGE

  // ---- fused epilogue (R3/R6-proven, unchanged) ----
  const float c0 = 640.0f;   // (D/2)/T
  const float c1 = 2.5f;     // 0.25/T
  float aR[4][4];
#pragma unroll
  for (int m = 0; m < 4; ++m)
#pragma unroll
    for (int v = 0; v < 4; ++v)
      aR[m][v] = a[rowBase + wr * 64 + m * 16 + rq * 4 + v];
  float aC[4];
#pragma unroll
  for (int n = 0; n < 4; ++n) aC[n] = a[colBase + wc * 64 + n * 16 + lx];

  // pass 1: acc -> S (diag -> -inf; positive logit += to_add, pos[] writes)
#pragma unroll
  for (int m = 0; m < 4; ++m)
#pragma unroll
    for (int n = 0; n < 4; ++n)
#pragma unroll
      for (int v = 0; v < 4; ++v) {
        int grow = rowBase + wr * 64 + m * 16 + rq * 4 + v;
        int gcol = colBase + wc * 64 + n * 16 + lx;
        float S = c0 - c1 * (acc[m][n][v] + aR[m][v] + aC[n]);
        if (gcol == grow) {
          S = -INFINITY;
        } else if (gcol == (grow ^ B_HALF)) {
          S += to_add;
          pos[grow] = S;   // S symmetric: also row gcol's positive
          pos[gcol] = S;
        }
        acc[m][n][v] = S;
      }

  // pass 2: row partials -> lsep[row][cb]
#pragma unroll
  for (int m = 0; m < 4; ++m)
#pragma unroll
    for (int v = 0; v < 4; ++v) {
      float pm = -INFINITY;
#pragma unroll
      for (int n = 0; n < 4; ++n) pm = fmaxf(pm, acc[m][n][v]);
#pragma unroll
      for (int x = 1; x < 16; x <<= 1) pm = fmaxf(pm, __shfl_xor(pm, x));
      float ps = 0.f;
#pragma unroll
      for (int n = 0; n < 4; ++n) ps += __expf(acc[m][n][v] - pm);
#pragma unroll
      for (int x = 1; x < 16; x <<= 1) ps += __shfl_xor(ps, x);
      if (lx == 0) red[wr * 64 + m * 16 + rq * 4 + v][wc] = make_float2(pm, ps);
    }
  __syncthreads();
  if (tid < 128) {
    float2 p0 = red[tid][0], p1 = red[tid][1];
    float M = fmaxf(p0.x, p1.x);
    float S = p0.y * __expf(p0.x - M) + p1.y * __expf(p1.x - M);
    lsep[(size_t)(rowBase + tid) * NGRP + cb] = M + logf(S);
  }

  // pass 3: column partials -> lsep[col][rb]  (off-diagonal tiles only)
  if (rb != cb) {
    __syncthreads();
#pragma unroll
    for (int n = 0; n < 4; ++n) {
      float cm = -INFINITY;
#pragma unroll
      for (int m = 0; m < 4; ++m)
#pragma unroll
        for (int v = 0; v < 4; ++v) cm = fmaxf(cm, acc[m][n][v]);
      cm = fmaxf(cm, __shfl_xor(cm, 16));
      cm = fmaxf(cm, __shfl_xor(cm, 32));
      float cs = 0.f;
#pragma unroll
      for (int m = 0; m < 4; ++m)
#pragma unroll
        for (int v = 0; v < 4; ++v) cs += __expf(acc[m][n][v] - cm);
      cs += __shfl_xor(cs, 16);
      cs += __shfl_xor(cs, 32);
      if (lane < 16) red[wc * 64 + n * 16 + lane][wr] = make_float2(cm, cs);
    }
    __syncthreads();
    if (tid < 128) {
      float2 p0 = red[tid][0], p1 = red[tid][1];
      float M = fmaxf(p0.x, p1.x);
      float S = p0.y * __expf(p0.x - M) + p1.y * __expf(p1.x - M);
      lsep[(size_t)(colBase + tid) * NGRP + rb] = M + logf(S);
    }
  }
}

// ---------------------------------------------------------------------------
// P2+P3: 16 blocks x 256 thr; last finisher sums 16 partials in fixed order
// and resets the counter (R6-proven).
// ---------------------------------------------------------------------------
__global__ __launch_bounds__(256) void reduce_final(
    const float* __restrict__ lsep, const float* __restrict__ pos,
    float* __restrict__ partial, float* __restrict__ out) {
  const int tid = threadIdx.x;
  const int row = blockIdx.x * 256 + tid;
  const float* lp = lsep + (size_t)row * NGRP;
  float M = lp[0];
#pragma unroll
  for (int k = 1; k < NGRP; ++k) M = fmaxf(M, lp[k]);
  float s = 0.f;
#pragma unroll
  for (int k = 0; k < NGRP; ++k) s += __expf(lp[k] - M);
  float contrib = (M + logf(s)) - pos[row];

  __shared__ float fr[256];
  fr[tid] = contrib;
  __syncthreads();
#pragma unroll
  for (int off = 128; off > 0; off >>= 1) {
    if (tid < off) fr[tid] += fr[tid + off];
    __syncthreads();
  }
  if (tid == 0) {
    partial[blockIdx.x] = fr[0];
    unsigned v = __hip_atomic_fetch_add(&red_done, 1u, __ATOMIC_ACQ_REL,
                                        __HIP_MEMORY_SCOPE_AGENT);
    if (v == 15u) {
      float tot = 0.f;
      for (int k = 0; k < 16; ++k) tot += partial[k];
      out[0] = tot * (1.0f / 4096.0f);
      __hip_atomic_store(&red_done, 0u, __ATOMIC_RELAXED,
                         __HIP_MEMORY_SCOPE_AGENT);
    }
  }
}

// ===========================================================================
extern "C" void kernel_launch(void* const* d_in, const int* in_sizes, int n_in,
                              void* d_out, int out_size, void* d_ws, size_t ws_size,
                              hipStream_t stream) {
  const float* mu_x    = (const float*)d_in[1];
  const float* sigma_x = (const float*)d_in[2];
  const float* mu_p    = (const float*)d_in[3];
  const float* sigma_p = (const float*)d_in[4];
  float* out = (float*)d_out;

  float to_add = (float)(-log((4095.0 - 1.0 / 5.0) / 4094.0));

  const size_t featB = (size_t)N_TOT * ROWB;        // 2 MB fp8 features
  char* ws = (char*)d_ws;
  unsigned char* Gf8 = (unsigned char*)(ws);
  float* a       = (float*)(ws + featB);                    // 16 KB
  float* lsep    = (float*)(ws + featB + 16384);            // 512 KB
  float* pos     = (float*)(ws + featB + 16384 + 524288);   // 16 KB
  float* partial = (float*)(ws + featB + 16384 + 524288 + 16384);

  prep_feat<<<dim3(256), dim3(256), 0, stream>>>(mu_x, sigma_x, mu_p, sigma_p,
                                                 Gf8, a);
  gemm_lse<<<dim3(NBLK), dim3(256), 0, stream>>>(Gf8, a, lsep, pos, to_add);
  reduce_final<<<dim3(16), dim3(256), 0, stream>>>(lsep, pos, partial, out);
}